// Round 9
// baseline (370.815 us; speedup 1.0000x reference)
//
#include <hip/hip_runtime.h>
#include <stdint.h>

// Workspace layout (float offsets)
#define WS_M2 0          // 16384 floats  (512 x 32)
#define WS_N2 16384      // 2048  floats  (64 x 32)
#define WS_WT 18432      // 131072 floats (32 x 4096), W transposed: Wt[r*4096+o]
#define WS_Z  149504     // 32768 floats  (1024 x 32)

// Direct global->LDS async copy, 16 B per lane. LDS dest is wave-uniform base
// (HW appends lane*16); global src must include lane*4 floats.
#define GLOAD_LDS16(gsrc, ldst)                                         \
    __builtin_amdgcn_global_load_lds(                                   \
        (const __attribute__((address_space(1))) uint32_t*)(gsrc),      \
        (__attribute__((address_space(3))) uint32_t*)(ldst), 16, 0, 0)

#define FMA4(A, X, mm) do { (A).x += (X).x*(mm); (A).y += (X).y*(mm); \
                            (A).z += (X).z*(mm); (A).w += (X).w*(mm); } while (0)

// ---------------------------------------------------------------------------
// Kernel A: collapse TT factor chains into small dense matrices. (unchanged)
// ---------------------------------------------------------------------------
__global__ __launch_bounds__(256) void precompute_kernel(
    const float* __restrict__ f0, const float* __restrict__ f1,
    const float* __restrict__ f2, const float* __restrict__ f3,
    const float* __restrict__ f4, const float* __restrict__ g0,
    const float* __restrict__ g1, const float* __restrict__ g2,
    float* __restrict__ ws)
{
    __shared__ float sA[8192];
    const int t = threadIdx.x;
    const int blk = blockIdx.x;
    if (blk < 8) {
        for (int i = t; i < 2048; i += 256) {
            int a01 = i >> 5, r2 = i & 31;
            int a0 = a01 >> 3, a1 = a01 & 7;
            float s = 0.f;
            #pragma unroll
            for (int r1 = 0; r1 < 32; ++r1)
                s += f0[a0*32 + r1] * f1[r1*256 + a1*32 + r2];
            sA[i] = s;
        }
        __syncthreads();
        for (int i = t; i < 2048; i += 256) {
            int a012 = blk*64 + (i >> 5), r3 = i & 31;
            int a01 = a012 >> 3, a2 = a012 & 7;
            float s = 0.f;
            #pragma unroll
            for (int r2 = 0; r2 < 32; ++r2)
                s += sA[a01*32 + r2] * f2[r2*256 + a2*32 + r3];
            ws[WS_M2 + a012*32 + r3] = s;
        }
    } else if (blk == 8) {
        for (int i = t; i < 2048; i += 256) {
            int a34 = i >> 5, s2 = i & 31;
            int a3 = a34 >> 3, a4 = a34 & 7;
            float s = 0.f;
            #pragma unroll
            for (int s1 = 0; s1 < 32; ++s1)
                s += f3[a3*32 + s1] * f4[s1*256 + a4*32 + s2];
            ws[WS_N2 + i] = s;
        }
    } else {
        const int j = blk - 9;   // 0..31, o-slice
        for (int i = t; i < 8192; i += 256) {
            int o01 = i >> 5, q = i & 31;
            int o0 = o01 >> 4, o1 = o01 & 15;
            float s = 0.f;
            #pragma unroll
            for (int p = 0; p < 32; ++p)
                s += g0[o0*32 + p] * g1[p*512 + o1*32 + q];
            sA[i] = s;
        }
        __syncthreads();
        for (int i = t; i < 4096; i += 256) {
            int o = j*128 + (i >> 5);
            int r = i & 31;
            int o01 = o >> 4, o2 = o & 15;
            float s = 0.f;
            #pragma unroll
            for (int q = 0; q < 32; ++q)
                s += sA[o01*32 + q] * g2[q*512 + o2*32 + r];
            ws[WS_WT + r*4096 + o] = s;
        }
    }
}

// ---------------------------------------------------------------------------
// Kernel B v9: v7 skeleton with x moved OFF the LDS pipe.
//   1024 blocks x 256 threads (4 waves), 1 batch/block, k-split: wave w owns
//   k in [128w, 128w+128) as 16 chunks of 8 k.
//   x: global->VGPR, 2 coalesced dwordx4 per k (compiler-scheduled vmcnt,
//      software-pipelined -- NO asm, NO clobbers in the k-loop).
//   M2: wave-private LDS double buffer (2 x 256 fl), staged T14-style:
//      register float4 load at chunk top, ds_write_b128 at chunk end
//      (wave-local in-order DS -> no barriers). Per k: ONE ds_read_b128
//      (tr*16B spans all 32 banks once -> conflict-free 8-lane broadcast).
//   Per k per thread: 2 VMEM + 1 LDS read + 32 FMAs (LDS-pipe load cut 3x
//   vs v7; VALU ~14 us becomes co-dominant).
// LDS map, s[10240] = 40 KB -> 4 blocks/CU (16 waves):
//   wave region R = s + w*2048:
//     k-loop: M2 dbuf R[0..512) (2 x 256)
//     after:  partials [32 r][64 m] pitch 64, m-octet XOR-rotated (aliases
//             dead M2 dbuf; own-wave in-order DS -> no barrier)
//   N2 [8192..10240) staged after barrier#1 via global_load_lds.
//   After reduce: T3t in w0 region [0..2048), T5 [2048..3072),
//                 spart [3072..3584)  (w1 region, dead).
// ---------------------------------------------------------------------------
__global__ __launch_bounds__(256, 4) void main_kernel(
    const float* __restrict__ x, const float* __restrict__ core,
    const float* __restrict__ ws, float* __restrict__ zout)
{
    __shared__ float s[10240];
    const int t = threadIdx.x;
    const int b = blockIdx.x;
    const int w    = __builtin_amdgcn_readfirstlane(t >> 6);  // wave 0..3
    const int lane = t & 63;
    const int tm = lane & 7;    // m-octet: m = tm*8 .. tm*8+7
    const int tr = lane >> 3;   // r-quad:  r = tr*4 .. tr*4+3

    float* __restrict__ R = s + w*2048;                        // wave region
    const float* __restrict__ xg = x + (size_t)b*32768 + w*8192 + tm*8;
    const float* __restrict__ mg = ws + WS_M2 + w*4096;

    // ---- prologue: stage M2 chunk 0 (8k x 32r = 256 fl) into dbuf slot 0
    {
        float4 n = *(const float4*)(mg + lane*4);
        *(float4*)(R + lane*4) = n;
    }

    float4 accA[4], accB[4];
    #pragma unroll
    for (int rr = 0; rr < 4; ++rr) {
        accA[rr].x = accA[rr].y = accA[rr].z = accA[rr].w = 0.f;
        accB[rr].x = accB[rr].y = accB[rr].z = accB[rr].w = 0.f;
    }

    #pragma unroll 1
    for (int c = 0; c < 16; ++c) {
        // issue-early: M2 chunk c+1 into registers (latency hides under compute)
        float4 n;
        if (c < 15) n = *(const float4*)(mg + (c+1)*256 + lane*4);
        // compute chunk c: 8 k; x from global regs, M2 broadcast from LDS
        const float* __restrict__ xt = xg + c*512;              // c*8k*64m
        const float* __restrict__ mt = R + (c&1)*256 + tr*4;
        #pragma unroll
        for (int kk = 0; kk < 8; ++kk) {
            float4 xlo = *(const float4*)(xt + kk*64);
            float4 xhi = *(const float4*)(xt + kk*64 + 4);
            float4 m4  = *(const float4*)(mt + kk*32);
            FMA4(accA[0], xlo, m4.x); FMA4(accB[0], xhi, m4.x);
            FMA4(accA[1], xlo, m4.y); FMA4(accB[1], xhi, m4.y);
            FMA4(accA[2], xlo, m4.z); FMA4(accB[2], xhi, m4.z);
            FMA4(accA[3], xlo, m4.w); FMA4(accB[3], xhi, m4.w);
        }
        // write-late: chunk c+1 into the other slot (slot last read at c-1)
        if (c < 15) *(float4*)(R + ((c+1)&1)*256 + lane*4) = n;
    }

    // ---- write partials into own region: [32 r][64 m] pitch 64,
    //      m-octet slot = (tm ^ (r&7))  (XOR rotation, conflict-free reads)
    #pragma unroll
    for (int rr = 0; rr < 4; ++rr) {
        const int r = tr*4 + rr;
        float* d = R + r*64 + ((tm ^ (r & 7)) << 3);
        d[0]=accA[rr].x; d[1]=accA[rr].y; d[2]=accA[rr].z; d[3]=accA[rr].w;
        d[4]=accB[rr].x; d[5]=accB[rr].y; d[6]=accB[rr].z; d[7]=accB[rr].w;
    }
    __syncthreads();   // barrier#1: all partials visible

    // ---- stage N2 (2048 fl) into [8192..10240), quarter per wave
    {
        const float* sn = ws + WS_N2 + w*512 + lane*4;
        GLOAD_LDS16(sn,       s + 8192 + w*512);
        GLOAD_LDS16(sn + 256, s + 8192 + w*512 + 256);
    }

    // ---- reduce over 4 k-quarters; final T3t lands in w0 region.
    //      thread (rr = t>>3, mo = t&7) owns octet slot (mo ^ (rr&7)):
    //      thread-exclusive addresses -> no barrier between read and write.
    {
        const int rr = t >> 3;
        const int mo = t & 7;
        const int off = rr*64 + ((mo ^ (rr & 7)) << 3);
        float sm[8];
        #pragma unroll
        for (int i = 0; i < 8; ++i)
            sm[i] = s[off + i] + s[2048 + off + i]
                  + s[4096 + off + i] + s[6144 + off + i];
        #pragma unroll
        for (int i = 0; i < 8; ++i) s[off + i] = sm[i];
    }
    asm volatile("s_waitcnt vmcnt(0)" ::: "memory");  // N2 landed
    __syncthreads();   // barrier#2: T3t + N2 visible

    // ---- phase 3: T5[r3,s2] = sum_m T3t[r3,m] * N2[m,s2] -> [2048..3072)
    {
        const int r3  = t >> 3;
        const int s2b = (t & 7) * 4;
        float a0=0.f, a1=0.f, a2=0.f, a3=0.f;
        #pragma unroll 8
        for (int m = 0; m < 64; ++m) {
            float av = s[r3*64 + (((m >> 3) ^ (r3 & 7)) << 3) + (m & 7)];
            const float* n = &s[8192 + m*32 + s2b];
            a0 += av*n[0]; a1 += av*n[1]; a2 += av*n[2]; a3 += av*n[3];
        }
        float* d = &s[2048 + r3*32 + s2b];   // w1 region (dead)
        d[0]=a0; d[1]=a1; d[2]=a2; d[3]=a3;
    }
    __syncthreads();   // barrier#3

    // ---- phase 4: z[ro] = sum_k T5[k] * core[k,ro]
    {
        const int ro2 = t & 15;
        const int kc  = t >> 4;
        const float2* core2 = (const float2*)core;
        float s0 = 0.f, s1 = 0.f;
        const int k0 = kc * 64;
        for (int k = k0; k < k0 + 64; ++k) {
            float tv = s[2048 + k];
            float2 cv = core2[k*16 + ro2];
            s0 += tv*cv.x; s1 += tv*cv.y;
        }
        s[3072 + kc*32 + ro2*2 + 0] = s0;
        s[3072 + kc*32 + ro2*2 + 1] = s1;
    }
    __syncthreads();   // barrier#4
    if (t < 32) {
        float acc = 0.f;
        #pragma unroll
        for (int kc = 0; kc < 16; ++kc) acc += s[3072 + kc*32 + t];
        zout[b*32 + t] = acc;
    }
}

// ---------------------------------------------------------------------------
// Kernel C: out[b,o] = sum_r z[b,r]*Wt[r,o] + bias[o]  (unchanged)
// ---------------------------------------------------------------------------
__global__ __launch_bounds__(256) void out_kernel(
    const float* __restrict__ ws, const float* __restrict__ bias,
    float* __restrict__ out)
{
    __shared__ float sW[8192];   // Wt tile [32][256]
    __shared__ float sZt[2176];  // z tile transposed [32 ro][68]
    __shared__ float sB[256];
    const int t  = threadIdx.x;
    const int bt = blockIdx.x;
    const int ot = blockIdx.y;

    {
        const float4* wt4 = (const float4*)(ws + WS_WT);
        float4* d = (float4*)sW;
        #pragma unroll
        for (int i = 0; i < 8; ++i) {
            int idx = i*256 + t;
            int ro = idx >> 6, oc = idx & 63;
            d[idx] = wt4[ro*1024 + ot*64 + oc];
        }
    }
    {
        const float4* z4 = (const float4*)(ws + WS_Z) + bt*512;
        #pragma unroll
        for (int i = 0; i < 2; ++i) {
            int idx = i*256 + t;
            int bl = idx >> 3, r4 = idx & 7;
            float4 v = z4[idx];
            sZt[(r4*4 + 0)*68 + bl] = v.x;
            sZt[(r4*4 + 1)*68 + bl] = v.y;
            sZt[(r4*4 + 2)*68 + bl] = v.z;
            sZt[(r4*4 + 3)*68 + bl] = v.w;
        }
    }
    if (t < 64) {
        const float4* b4 = (const float4*)bias + ot*64;
        ((float4*)sB)[t] = b4[t];
    }
    __syncthreads();

    const int oc = t & 63;
    const int bg = t >> 6;
    const float4* sW4 = (const float4*)sW;
    const float4 bv = ((const float4*)sB)[oc];
    float4* out4 = (float4*)out;

    for (int bi = 0; bi < 16; bi += 4) {
        const int bl = bg*16 + bi;
        float4 a0 = bv, a1 = bv, a2 = bv, a3 = bv;
        #pragma unroll
        for (int ro = 0; ro < 32; ++ro) {
            float4 w = sW4[ro*64 + oc];
            float4 z = *(const float4*)&sZt[ro*68 + bl];
            a0.x += z.x*w.x; a0.y += z.x*w.y; a0.z += z.x*w.z; a0.w += z.x*w.w;
            a1.x += z.y*w.x; a1.y += z.y*w.y; a1.z += z.y*w.z; a1.w += z.y*w.w;
            a2.x += z.z*w.x; a2.y += z.z*w.y; a2.z += z.z*w.z; a2.w += z.z*w.w;
            a3.x += z.w*w.x; a3.y += z.w*w.y; a3.z += z.w*w.z; a3.w += z.w*w.w;
        }
        const size_t obase = (size_t)(bt*64 + bl) * 1024 + ot*64 + oc;
        out4[obase + 0*1024] = a0;
        out4[obase + 1*1024] = a1;
        out4[obase + 2*1024] = a2;
        out4[obase + 3*1024] = a3;
    }
}

extern "C" void kernel_launch(void* const* d_in, const int* in_sizes, int n_in,
                              void* d_out, int out_size, void* d_ws, size_t ws_size,
                              hipStream_t stream)
{
    const float* x    = (const float*)d_in[0];
    const float* f0   = (const float*)d_in[1];
    const float* f1   = (const float*)d_in[2];
    const float* f2   = (const float*)d_in[3];
    const float* f3   = (const float*)d_in[4];
    const float* f4   = (const float*)d_in[5];
    const float* core = (const float*)d_in[6];
    const float* g0   = (const float*)d_in[7];
    const float* g1   = (const float*)d_in[8];
    const float* g2   = (const float*)d_in[9];
    const float* bias = (const float*)d_in[10];
    float* ws  = (float*)d_ws;
    float* out = (float*)d_out;

    precompute_kernel<<<41, 256, 0, stream>>>(f0, f1, f2, f3, f4, g0, g1, g2, ws);
    main_kernel<<<1024, 256, 0, stream>>>(x, core, ws, ws + WS_Z);
    out_kernel<<<dim3(16, 16), 256, 0, stream>>>(ws, bias, out);
}

// Round 10
// 276.837 us; speedup vs baseline: 1.3395x; 1.3395x over previous
//
#include <hip/hip_runtime.h>
#include <stdint.h>

// Workspace layout (float offsets)
#define WS_M2 0          // 16384 floats  (512 x 32)
#define WS_N2 16384      // 2048  floats  (64 x 32)
#define WS_WT 18432      // 131072 floats (32 x 4096), W transposed: Wt[r*4096+o]
#define WS_Z  149504     // 32768 floats  (1024 x 32)

// Direct global->LDS async copy, 16 B per lane. LDS dest is wave-uniform base
// (HW appends lane*16); global src must include lane*4 floats.
#define GLOAD_LDS16(gsrc, ldst)                                         \
    __builtin_amdgcn_global_load_lds(                                   \
        (const __attribute__((address_space(1))) uint32_t*)(gsrc),      \
        (__attribute__((address_space(3))) uint32_t*)(ldst), 16, 0, 0)

#define FMA4(A, X, mm) do { (A).x += (X).x*(mm); (A).y += (X).y*(mm); \
                            (A).z += (X).z*(mm); (A).w += (X).w*(mm); } while (0)

// ---------------------------------------------------------------------------
// Kernel A: collapse TT factor chains into small dense matrices. (unchanged)
// ---------------------------------------------------------------------------
__global__ __launch_bounds__(256) void precompute_kernel(
    const float* __restrict__ f0, const float* __restrict__ f1,
    const float* __restrict__ f2, const float* __restrict__ f3,
    const float* __restrict__ f4, const float* __restrict__ g0,
    const float* __restrict__ g1, const float* __restrict__ g2,
    float* __restrict__ ws)
{
    __shared__ float sA[8192];
    const int t = threadIdx.x;
    const int blk = blockIdx.x;
    if (blk < 8) {
        for (int i = t; i < 2048; i += 256) {
            int a01 = i >> 5, r2 = i & 31;
            int a0 = a01 >> 3, a1 = a01 & 7;
            float s = 0.f;
            #pragma unroll
            for (int r1 = 0; r1 < 32; ++r1)
                s += f0[a0*32 + r1] * f1[r1*256 + a1*32 + r2];
            sA[i] = s;
        }
        __syncthreads();
        for (int i = t; i < 2048; i += 256) {
            int a012 = blk*64 + (i >> 5), r3 = i & 31;
            int a01 = a012 >> 3, a2 = a012 & 7;
            float s = 0.f;
            #pragma unroll
            for (int r2 = 0; r2 < 32; ++r2)
                s += sA[a01*32 + r2] * f2[r2*256 + a2*32 + r3];
            ws[WS_M2 + a012*32 + r3] = s;
        }
    } else if (blk == 8) {
        for (int i = t; i < 2048; i += 256) {
            int a34 = i >> 5, s2 = i & 31;
            int a3 = a34 >> 3, a4 = a34 & 7;
            float s = 0.f;
            #pragma unroll
            for (int s1 = 0; s1 < 32; ++s1)
                s += f3[a3*32 + s1] * f4[s1*256 + a4*32 + s2];
            ws[WS_N2 + i] = s;
        }
    } else {
        const int j = blk - 9;   // 0..31, o-slice
        for (int i = t; i < 8192; i += 256) {
            int o01 = i >> 5, q = i & 31;
            int o0 = o01 >> 4, o1 = o01 & 15;
            float s = 0.f;
            #pragma unroll
            for (int p = 0; p < 32; ++p)
                s += g0[o0*32 + p] * g1[p*512 + o1*32 + q];
            sA[i] = s;
        }
        __syncthreads();
        for (int i = t; i < 4096; i += 256) {
            int o = j*128 + (i >> 5);
            int r = i & 31;
            int o01 = o >> 4, o2 = o & 15;
            float s = 0.f;
            #pragma unroll
            for (int q = 0; q < 32; ++q)
                s += sA[o01*32 + q] * g2[q*512 + o2*32 + r];
            ws[WS_WT + r*4096 + o] = s;
        }
    }
}

// ---------------------------------------------------------------------------
// Kernel B v10: 1024 blocks x 512 threads (8 waves), 1 batch/block, 8-way
// k-split (wave w: k in [64w, 64w+64)).
//   M2: each wave prestages its whole 64k x 32r slice (2048 fl = 8 KB) into
//       its LDS region ONCE via global_load_lds; one barrier; k-loop has NO
//       staging, NO asm, NO barriers.
//   x:  global -> VGPR, 2 coalesced dwordx4 per k (used once, exact traffic,
//       compiler-scheduled vmcnt + pipelining).
//   Per k per thread (tm=lane&7, tr=lane>>3; tile 8m x 4r): 2 VMEM + ONE
//   ds_read_b128 (tr*16B: 8 distinct addrs cover all 32 banks once,
//   8-lane broadcast -> conflict-free) + 32 FMAs into accA[4]/accB[4].
// LDS map, s[18432] = 72 KB -> 2 blocks/CU (16 waves/CU, 4/SIMD):
//   wave region R = s + w*2048: M2 slice during k-loop; afterwards partials
//   [32 r][64 m] pitch 64, m-octet XOR-rotated (own-wave aliasing, in-order
//   DS -> no extra barrier).
//   N2 [16384..18432) staged after barrier#1 (1 gload_lds per wave).
//   After reduce: T3t in w0 region [0..2048); T5 [2048..3072) (w1, dead);
//   spart [6144..7168) (w3, dead).
// ---------------------------------------------------------------------------
__global__ __launch_bounds__(512, 4) void main_kernel(
    const float* __restrict__ x, const float* __restrict__ core,
    const float* __restrict__ ws, float* __restrict__ zout)
{
    __shared__ float s[18432];
    const int t = threadIdx.x;
    const int b = blockIdx.x;
    const int w    = __builtin_amdgcn_readfirstlane(t >> 6);  // wave 0..7
    const int lane = t & 63;
    const int tm = lane & 7;    // m-octet: m = tm*8 .. tm*8+7
    const int tr = lane >> 3;   // r-quad:  r = tr*4 .. tr*4+3

    float* __restrict__ R = s + w*2048;                        // wave region
    const float* __restrict__ xg = x + (size_t)b*32768 + w*4096 + tm*8;
    const float* __restrict__ mg = ws + WS_M2 + w*2048;        // k-eighth

    // ---- prestage this wave's M2 slice (2048 fl) into R, once
    #pragma unroll
    for (int i = 0; i < 8; ++i)
        GLOAD_LDS16(mg + i*256 + lane*4, R + i*256);
    __syncthreads();   // drains vmcnt; M2 resident for the whole k-loop

    float4 accA[4], accB[4];
    #pragma unroll
    for (int rr = 0; rr < 4; ++rr) {
        accA[rr].x = accA[rr].y = accA[rr].z = accA[rr].w = 0.f;
        accB[rr].x = accB[rr].y = accB[rr].z = accB[rr].w = 0.f;
    }

    // ---- k-loop: 2 global dwordx4 + 1 ds_read_b128 + 32 FMAs per k
    #pragma unroll 4
    for (int k = 0; k < 64; ++k) {
        float4 xlo = *(const float4*)(xg + k*64);
        float4 xhi = *(const float4*)(xg + k*64 + 4);
        float4 m4  = *(const float4*)(R + k*32 + tr*4);
        FMA4(accA[0], xlo, m4.x); FMA4(accB[0], xhi, m4.x);
        FMA4(accA[1], xlo, m4.y); FMA4(accB[1], xhi, m4.y);
        FMA4(accA[2], xlo, m4.z); FMA4(accB[2], xhi, m4.z);
        FMA4(accA[3], xlo, m4.w); FMA4(accB[3], xhi, m4.w);
    }

    // ---- write partials into own region: [32 r][64 m] pitch 64,
    //      m-octet slot = (tm ^ (r&7))  (XOR rotation, conflict-free reads)
    #pragma unroll
    for (int rr = 0; rr < 4; ++rr) {
        const int r = tr*4 + rr;
        float* d = R + r*64 + ((tm ^ (r & 7)) << 3);
        d[0]=accA[rr].x; d[1]=accA[rr].y; d[2]=accA[rr].z; d[3]=accA[rr].w;
        d[4]=accB[rr].x; d[5]=accB[rr].y; d[6]=accB[rr].z; d[7]=accB[rr].w;
    }
    __syncthreads();   // barrier#1: all partials visible

    // ---- stage N2 (2048 fl) into [16384..18432), eighth per wave
    GLOAD_LDS16(ws + WS_N2 + w*256 + lane*4, s + 16384 + w*256);

    // ---- reduce over 8 k-eighths; final T3t lands in w0 region.
    //      thread t: rr = t>>4 (row), mq = t&15 (m-quad); stored slot for
    //      octet om = mq>>1 is (om ^ (rr&7)); within-octet base (mq&1)*4.
    //      Thread-exclusive addresses -> no barrier between read and write.
    {
        const int rr = t >> 4;
        const int mq = t & 15;
        const int off = rr*64 + (((mq >> 1) ^ (rr & 7)) << 3) + (mq & 1)*4;
        float sm[4];
        #pragma unroll
        for (int i = 0; i < 4; ++i)
            sm[i] = s[off + i]         + s[2048 + off + i]
                  + s[4096 + off + i]  + s[6144 + off + i]
                  + s[8192 + off + i]  + s[10240 + off + i]
                  + s[12288 + off + i] + s[14336 + off + i];
        #pragma unroll
        for (int i = 0; i < 4; ++i) s[off + i] = sm[i];
    }
    asm volatile("s_waitcnt vmcnt(0)" ::: "memory");  // N2 landed
    __syncthreads();   // barrier#2: T3t + N2 visible

    // ---- phase 3: T5[r3,s2] = sum_m T3t[r3,m] * N2[m,s2] -> [2048..3072)
    //      512 threads: r3 = t>>4, s2 pair = (t&15)*2
    {
        const int r3 = t >> 4;
        const int cp = (t & 15) * 2;
        float a0 = 0.f, a1 = 0.f;
        #pragma unroll 8
        for (int m = 0; m < 64; ++m) {
            float av = s[r3*64 + (((m >> 3) ^ (r3 & 7)) << 3) + (m & 7)];
            const float* n = &s[16384 + m*32 + cp];
            a0 += av*n[0]; a1 += av*n[1];
        }
        s[2048 + r3*32 + cp + 0] = a0;   // w1 region (dead)
        s[2048 + r3*32 + cp + 1] = a1;
    }
    __syncthreads();   // barrier#3

    // ---- phase 4: z[ro] = sum_k T5[k] * core[k,ro]
    //      512 threads: kc = t>>4 (32-k chunk), ro2 = t&15 (2 ro)
    {
        const int ro2 = t & 15;
        const int kc  = t >> 4;
        const float2* core2 = (const float2*)core;
        float s0 = 0.f, s1 = 0.f;
        const int k0 = kc * 32;
        for (int k = k0; k < k0 + 32; ++k) {
            float tv = s[2048 + k];
            float2 cv = core2[k*16 + ro2];
            s0 += tv*cv.x; s1 += tv*cv.y;
        }
        s[6144 + kc*32 + ro2*2 + 0] = s0;   // w3 region (dead)
        s[6144 + kc*32 + ro2*2 + 1] = s1;
    }
    __syncthreads();   // barrier#4
    if (t < 32) {
        float acc = 0.f;
        #pragma unroll
        for (int kc = 0; kc < 32; ++kc) acc += s[6144 + kc*32 + t];
        zout[b*32 + t] = acc;
    }
}

// ---------------------------------------------------------------------------
// Kernel C: out[b,o] = sum_r z[b,r]*Wt[r,o] + bias[o]  (unchanged)
// ---------------------------------------------------------------------------
__global__ __launch_bounds__(256) void out_kernel(
    const float* __restrict__ ws, const float* __restrict__ bias,
    float* __restrict__ out)
{
    __shared__ float sW[8192];   // Wt tile [32][256]
    __shared__ float sZt[2176];  // z tile transposed [32 ro][68]
    __shared__ float sB[256];
    const int t  = threadIdx.x;
    const int bt = blockIdx.x;
    const int ot = blockIdx.y;

    {
        const float4* wt4 = (const float4*)(ws + WS_WT);
        float4* d = (float4*)sW;
        #pragma unroll
        for (int i = 0; i < 8; ++i) {
            int idx = i*256 + t;
            int ro = idx >> 6, oc = idx & 63;
            d[idx] = wt4[ro*1024 + ot*64 + oc];
        }
    }
    {
        const float4* z4 = (const float4*)(ws + WS_Z) + bt*512;
        #pragma unroll
        for (int i = 0; i < 2; ++i) {
            int idx = i*256 + t;
            int bl = idx >> 3, r4 = idx & 7;
            float4 v = z4[idx];
            sZt[(r4*4 + 0)*68 + bl] = v.x;
            sZt[(r4*4 + 1)*68 + bl] = v.y;
            sZt[(r4*4 + 2)*68 + bl] = v.z;
            sZt[(r4*4 + 3)*68 + bl] = v.w;
        }
    }
    if (t < 64) {
        const float4* b4 = (const float4*)bias + ot*64;
        ((float4*)sB)[t] = b4[t];
    }
    __syncthreads();

    const int oc = t & 63;
    const int bg = t >> 6;
    const float4* sW4 = (const float4*)sW;
    const float4 bv = ((const float4*)sB)[oc];
    float4* out4 = (float4*)out;

    for (int bi = 0; bi < 16; bi += 4) {
        const int bl = bg*16 + bi;
        float4 a0 = bv, a1 = bv, a2 = bv, a3 = bv;
        #pragma unroll
        for (int ro = 0; ro < 32; ++ro) {
            float4 w = sW4[ro*64 + oc];
            float4 z = *(const float4*)&sZt[ro*68 + bl];
            a0.x += z.x*w.x; a0.y += z.x*w.y; a0.z += z.x*w.z; a0.w += z.x*w.w;
            a1.x += z.y*w.x; a1.y += z.y*w.y; a1.z += z.y*w.z; a1.w += z.y*w.w;
            a2.x += z.z*w.x; a2.y += z.z*w.y; a2.z += z.z*w.z; a2.w += z.z*w.w;
            a3.x += z.w*w.x; a3.y += z.w*w.y; a3.z += z.w*w.z; a3.w += z.w*w.w;
        }
        const size_t obase = (size_t)(bt*64 + bl) * 1024 + ot*64 + oc;
        out4[obase + 0*1024] = a0;
        out4[obase + 1*1024] = a1;
        out4[obase + 2*1024] = a2;
        out4[obase + 3*1024] = a3;
    }
}

extern "C" void kernel_launch(void* const* d_in, const int* in_sizes, int n_in,
                              void* d_out, int out_size, void* d_ws, size_t ws_size,
                              hipStream_t stream)
{
    const float* x    = (const float*)d_in[0];
    const float* f0   = (const float*)d_in[1];
    const float* f1   = (const float*)d_in[2];
    const float* f2   = (const float*)d_in[3];
    const float* f3   = (const float*)d_in[4];
    const float* f4   = (const float*)d_in[5];
    const float* core = (const float*)d_in[6];
    const float* g0   = (const float*)d_in[7];
    const float* g1   = (const float*)d_in[8];
    const float* g2   = (const float*)d_in[9];
    const float* bias = (const float*)d_in[10];
    float* ws  = (float*)d_ws;
    float* out = (float*)d_out;

    precompute_kernel<<<41, 256, 0, stream>>>(f0, f1, f2, f3, f4, g0, g1, g2, ws);
    main_kernel<<<1024, 512, 0, stream>>>(x, core, ws, ws + WS_Z);
    out_kernel<<<dim3(16, 16), 256, 0, stream>>>(ws, bias, out);
}

// Round 11
// 263.973 us; speedup vs baseline: 1.4047x; 1.0487x over previous
//
#include <hip/hip_runtime.h>
#include <stdint.h>

// Workspace layout (float offsets)
#define WS_M2 0          // 16384 floats  (512 x 32)
#define WS_N2 16384      // 2048  floats  (64 x 32)
#define WS_WT 18432      // 131072 floats (32 x 4096), W transposed: Wt[r*4096+o]
#define WS_Z  149504     // 32768 floats  (1024 x 32)

// Direct global->LDS async copy, 16 B per lane. LDS dest is wave-uniform base
// (HW appends lane*16); global src must include lane*4 floats.
#define GLOAD_LDS16(gsrc, ldst)                                         \
    __builtin_amdgcn_global_load_lds(                                   \
        (const __attribute__((address_space(1))) uint32_t*)(gsrc),      \
        (__attribute__((address_space(3))) uint32_t*)(ldst), 16, 0, 0)

#define FMA4(A, X, mm) do { (A).x += (X).x*(mm); (A).y += (X).y*(mm); \
                            (A).z += (X).z*(mm); (A).w += (X).w*(mm); } while (0)

// ---------------------------------------------------------------------------
// Kernel A: collapse TT factor chains into small dense matrices. (unchanged)
// ---------------------------------------------------------------------------
__global__ __launch_bounds__(256) void precompute_kernel(
    const float* __restrict__ f0, const float* __restrict__ f1,
    const float* __restrict__ f2, const float* __restrict__ f3,
    const float* __restrict__ f4, const float* __restrict__ g0,
    const float* __restrict__ g1, const float* __restrict__ g2,
    float* __restrict__ ws)
{
    __shared__ float sA[8192];
    const int t = threadIdx.x;
    const int blk = blockIdx.x;
    if (blk < 8) {
        for (int i = t; i < 2048; i += 256) {
            int a01 = i >> 5, r2 = i & 31;
            int a0 = a01 >> 3, a1 = a01 & 7;
            float s = 0.f;
            #pragma unroll
            for (int r1 = 0; r1 < 32; ++r1)
                s += f0[a0*32 + r1] * f1[r1*256 + a1*32 + r2];
            sA[i] = s;
        }
        __syncthreads();
        for (int i = t; i < 2048; i += 256) {
            int a012 = blk*64 + (i >> 5), r3 = i & 31;
            int a01 = a012 >> 3, a2 = a012 & 7;
            float s = 0.f;
            #pragma unroll
            for (int r2 = 0; r2 < 32; ++r2)
                s += sA[a01*32 + r2] * f2[r2*256 + a2*32 + r3];
            ws[WS_M2 + a012*32 + r3] = s;
        }
    } else if (blk == 8) {
        for (int i = t; i < 2048; i += 256) {
            int a34 = i >> 5, s2 = i & 31;
            int a3 = a34 >> 3, a4 = a34 & 7;
            float s = 0.f;
            #pragma unroll
            for (int s1 = 0; s1 < 32; ++s1)
                s += f3[a3*32 + s1] * f4[s1*256 + a4*32 + s2];
            ws[WS_N2 + i] = s;
        }
    } else {
        const int j = blk - 9;   // 0..31, o-slice
        for (int i = t; i < 8192; i += 256) {
            int o01 = i >> 5, q = i & 31;
            int o0 = o01 >> 4, o1 = o01 & 15;
            float s = 0.f;
            #pragma unroll
            for (int p = 0; p < 32; ++p)
                s += g0[o0*32 + p] * g1[p*512 + o1*32 + q];
            sA[i] = s;
        }
        __syncthreads();
        for (int i = t; i < 4096; i += 256) {
            int o = j*128 + (i >> 5);
            int r = i & 31;
            int o01 = o >> 4, o2 = o & 15;
            float s = 0.f;
            #pragma unroll
            for (int q = 0; q < 32; ++q)
                s += sA[o01*32 + q] * g2[q*512 + o2*32 + r];
            ws[WS_WT + r*4096 + o] = s;
        }
    }
}

// ---------------------------------------------------------------------------
// Kernel B v11: v7 structure + DEPTH-2 ring (3 slots) at UNCHANGED occupancy.
//   1024 blocks x 256 threads (4 waves), 1 batch/block, k-split: wave w owns
//   k in [128w, 128w+128) as 16 chunks of 8 k. All VMEM via global_load_lds
//   into wave-private ring buffers; at iter c stage chunk c+2 (3 loads: x 2,
//   M2 1) into slot (c+2)%3, then COUNTED s_waitcnt vmcnt(6) -- 2 chunks in
//   flight, ~1024 cyc cover >= HBM-miss latency. No barriers in the k-loop.
//   Compute per k: thread (tm=lane&7, tr=lane>>3) owns 8m x 4r; 2 b128 x +
//   1 b128 M2 (conflict-free) + 32 FMAs into float4 accA[4]/accB[4].
// LDS map, s[10240] = 40 KB -> 4 blocks/CU (16 waves, same as v7):
//   wave region R = s + w*2560:
//     k-loop: x ring R[0..1536) (3 x 512), M2 ring R[1536..2304) (3 x 256)
//     after:  partials [32 r][64 m] pitch 64, m-octet XOR-rotated, at
//             R[0..2048) (aliases dead ring; own-wave ordering -> no barrier)
//             N2 quarter (rows 16w..16w+16) at R[2048..2560), staged after
//             barrier#1 via 2 global_load_lds.
//   After reduce: T3t in w0 region [0..2048); T5 [2560..3584) (w1, dead);
//   spart [5120..5632) (w2, dead).
// ---------------------------------------------------------------------------
__global__ __launch_bounds__(256, 4) void main_kernel(
    const float* __restrict__ x, const float* __restrict__ core,
    const float* __restrict__ ws, float* __restrict__ zout)
{
    __shared__ float s[10240];
    const int t = threadIdx.x;
    const int b = blockIdx.x;
    const int w    = __builtin_amdgcn_readfirstlane(t >> 6);  // wave 0..3
    const int lane = t & 63;
    const int tm = lane & 7;    // m-octet: m = tm*8 .. tm*8+7
    const int tr = lane >> 3;   // r-quad:  r = tr*4 .. tr*4+3

    float* __restrict__ R = s + w*2560;                        // wave region
    const float* __restrict__ xg = x + (size_t)b*32768 + w*8192;
    const float* __restrict__ mg = ws + WS_M2 + w*4096;

    // ---- prologue: stage chunks 0,1 (6 loads in flight)
    #pragma unroll
    for (int j = 0; j < 2; ++j) {
        GLOAD_LDS16(xg + j*512 + lane*4,       R + j*512);
        GLOAD_LDS16(xg + j*512 + 256 + lane*4, R + j*512 + 256);
        GLOAD_LDS16(mg + j*256 + lane*4,       R + 1536 + j*256);
    }

    float4 accA[4], accB[4];
    #pragma unroll
    for (int rr = 0; rr < 4; ++rr) {
        accA[rr].x = accA[rr].y = accA[rr].z = accA[rr].w = 0.f;
        accB[rr].x = accB[rr].y = accB[rr].z = accB[rr].w = 0.f;
    }

    #pragma unroll 1
    for (int c = 0; c < 16; ++c) {
        if (c < 14) {   // stage chunk c+2 into ring slot (c+2)%3
            const int d = c + 2;
            const int sl = d % 3;
            const float* sx = xg + d*512 + lane*4;
            float* dx = R + sl*512;
            GLOAD_LDS16(sx,       dx);
            GLOAD_LDS16(sx + 256, dx + 256);
            GLOAD_LDS16(mg + d*256 + lane*4, R + 1536 + sl*256);
            asm volatile("s_waitcnt vmcnt(6)" ::: "memory");
        } else if (c == 14) {
            asm volatile("s_waitcnt vmcnt(3)" ::: "memory");
        } else {
            asm volatile("s_waitcnt vmcnt(0)" ::: "memory");
        }
        // compute chunk c: 8 k, all operands from wave-private LDS
        const int sl = c % 3;
        const float* __restrict__ xt = R + sl*512 + tm*8;
        const float* __restrict__ mt = R + 1536 + sl*256 + tr*4;
        #pragma unroll
        for (int kk = 0; kk < 8; ++kk) {
            float4 xlo = *(const float4*)(xt + kk*64);
            float4 xhi = *(const float4*)(xt + kk*64 + 4);
            float4 m4  = *(const float4*)(mt + kk*32);
            FMA4(accA[0], xlo, m4.x); FMA4(accB[0], xhi, m4.x);
            FMA4(accA[1], xlo, m4.y); FMA4(accB[1], xhi, m4.y);
            FMA4(accA[2], xlo, m4.z); FMA4(accB[2], xhi, m4.z);
            FMA4(accA[3], xlo, m4.w); FMA4(accB[3], xhi, m4.w);
        }
    }

    // ---- write partials into own region: [32 r][64 m] pitch 64,
    //      m-octet slot = (tm ^ (r&7))  (XOR rotation, conflict-free reads)
    #pragma unroll
    for (int rr = 0; rr < 4; ++rr) {
        const int r = tr*4 + rr;
        float* d = R + r*64 + ((tm ^ (r & 7)) << 3);
        d[0]=accA[rr].x; d[1]=accA[rr].y; d[2]=accA[rr].z; d[3]=accA[rr].w;
        d[4]=accB[rr].x; d[5]=accB[rr].y; d[6]=accB[rr].z; d[7]=accB[rr].w;
    }
    __syncthreads();   // barrier#1: all partials visible

    // ---- stage N2 quarter (rows 16w..16w+16) into R[2048..2560)
    {
        const float* sn = ws + WS_N2 + w*512 + lane*4;
        GLOAD_LDS16(sn,       R + 2048);
        GLOAD_LDS16(sn + 256, R + 2048 + 256);
    }

    // ---- reduce over 4 k-quarters; final T3t lands in w0 region.
    //      thread (rr = t>>3, mo = t&7) owns octet slot (mo ^ (rr&7)):
    //      thread-exclusive addresses -> no barrier between read and write.
    {
        const int rr = t >> 3;
        const int mo = t & 7;
        const int off = rr*64 + ((mo ^ (rr & 7)) << 3);
        float sm[8];
        #pragma unroll
        for (int i = 0; i < 8; ++i)
            sm[i] = s[off + i] + s[2560 + off + i]
                  + s[5120 + off + i] + s[7680 + off + i];
        #pragma unroll
        for (int i = 0; i < 8; ++i) s[off + i] = sm[i];
    }
    asm volatile("s_waitcnt vmcnt(0)" ::: "memory");  // N2 landed
    __syncthreads();   // barrier#2: T3t + N2 visible

    // ---- phase 3: T5[r3,s2] = sum_m T3t[r3,m] * N2[m,s2] -> [2560..3584)
    //      N2[m][c] at s[(m>>4)*2560 + 2048 + (m&15)*32 + c]
    {
        const int r3  = t >> 3;
        const int s2b = (t & 7) * 4;
        float a0=0.f, a1=0.f, a2=0.f, a3=0.f;
        #pragma unroll 8
        for (int m = 0; m < 64; ++m) {
            float av = s[r3*64 + (((m >> 3) ^ (r3 & 7)) << 3) + (m & 7)];
            const float* n = &s[(m >> 4)*2560 + 2048 + (m & 15)*32 + s2b];
            a0 += av*n[0]; a1 += av*n[1]; a2 += av*n[2]; a3 += av*n[3];
        }
        float* d = &s[2560 + r3*32 + s2b];   // w1 region (dead)
        d[0]=a0; d[1]=a1; d[2]=a2; d[3]=a3;
    }
    __syncthreads();   // barrier#3

    // ---- phase 4: z[ro] = sum_k T5[k] * core[k,ro]
    {
        const int ro2 = t & 15;
        const int kc  = t >> 4;
        const float2* core2 = (const float2*)core;
        float s0 = 0.f, s1 = 0.f;
        const int k0 = kc * 64;
        for (int k = k0; k < k0 + 64; ++k) {
            float tv = s[2560 + k];
            float2 cv = core2[k*16 + ro2];
            s0 += tv*cv.x; s1 += tv*cv.y;
        }
        s[5120 + kc*32 + ro2*2 + 0] = s0;   // w2 region (dead)
        s[5120 + kc*32 + ro2*2 + 1] = s1;
    }
    __syncthreads();   // barrier#4
    if (t < 32) {
        float acc = 0.f;
        #pragma unroll
        for (int kc = 0; kc < 16; ++kc) acc += s[5120 + kc*32 + t];
        zout[b*32 + t] = acc;
    }
}

// ---------------------------------------------------------------------------
// Kernel C: out[b,o] = sum_r z[b,r]*Wt[r,o] + bias[o]  (unchanged)
// ---------------------------------------------------------------------------
__global__ __launch_bounds__(256) void out_kernel(
    const float* __restrict__ ws, const float* __restrict__ bias,
    float* __restrict__ out)
{
    __shared__ float sW[8192];   // Wt tile [32][256]
    __shared__ float sZt[2176];  // z tile transposed [32 ro][68]
    __shared__ float sB[256];
    const int t  = threadIdx.x;
    const int bt = blockIdx.x;
    const int ot = blockIdx.y;

    {
        const float4* wt4 = (const float4*)(ws + WS_WT);
        float4* d = (float4*)sW;
        #pragma unroll
        for (int i = 0; i < 8; ++i) {
            int idx = i*256 + t;
            int ro = idx >> 6, oc = idx & 63;
            d[idx] = wt4[ro*1024 + ot*64 + oc];
        }
    }
    {
        const float4* z4 = (const float4*)(ws + WS_Z) + bt*512;
        #pragma unroll
        for (int i = 0; i < 2; ++i) {
            int idx = i*256 + t;
            int bl = idx >> 3, r4 = idx & 7;
            float4 v = z4[idx];
            sZt[(r4*4 + 0)*68 + bl] = v.x;
            sZt[(r4*4 + 1)*68 + bl] = v.y;
            sZt[(r4*4 + 2)*68 + bl] = v.z;
            sZt[(r4*4 + 3)*68 + bl] = v.w;
        }
    }
    if (t < 64) {
        const float4* b4 = (const float4*)bias + ot*64;
        ((float4*)sB)[t] = b4[t];
    }
    __syncthreads();

    const int oc = t & 63;
    const int bg = t >> 6;
    const float4* sW4 = (const float4*)sW;
    const float4 bv = ((const float4*)sB)[oc];
    float4* out4 = (float4*)out;

    for (int bi = 0; bi < 16; bi += 4) {
        const int bl = bg*16 + bi;
        float4 a0 = bv, a1 = bv, a2 = bv, a3 = bv;
        #pragma unroll
        for (int ro = 0; ro < 32; ++ro) {
            float4 w = sW4[ro*64 + oc];
            float4 z = *(const float4*)&sZt[ro*68 + bl];
            a0.x += z.x*w.x; a0.y += z.x*w.y; a0.z += z.x*w.z; a0.w += z.x*w.w;
            a1.x += z.y*w.x; a1.y += z.y*w.y; a1.z += z.y*w.z; a1.w += z.y*w.w;
            a2.x += z.z*w.x; a2.y += z.z*w.y; a2.z += z.z*w.z; a2.w += z.z*w.w;
            a3.x += z.w*w.x; a3.y += z.w*w.y; a3.z += z.w*w.z; a3.w += z.w*w.w;
        }
        const size_t obase = (size_t)(bt*64 + bl) * 1024 + ot*64 + oc;
        out4[obase + 0*1024] = a0;
        out4[obase + 1*1024] = a1;
        out4[obase + 2*1024] = a2;
        out4[obase + 3*1024] = a3;
    }
}

extern "C" void kernel_launch(void* const* d_in, const int* in_sizes, int n_in,
                              void* d_out, int out_size, void* d_ws, size_t ws_size,
                              hipStream_t stream)
{
    const float* x    = (const float*)d_in[0];
    const float* f0   = (const float*)d_in[1];
    const float* f1   = (const float*)d_in[2];
    const float* f2   = (const float*)d_in[3];
    const float* f3   = (const float*)d_in[4];
    const float* f4   = (const float*)d_in[5];
    const float* core = (const float*)d_in[6];
    const float* g0   = (const float*)d_in[7];
    const float* g1   = (const float*)d_in[8];
    const float* g2   = (const float*)d_in[9];
    const float* bias = (const float*)d_in[10];
    float* ws  = (float*)d_ws;
    float* out = (float*)d_out;

    precompute_kernel<<<41, 256, 0, stream>>>(f0, f1, f2, f3, f4, g0, g1, g2, ws);
    main_kernel<<<1024, 256, 0, stream>>>(x, core, ws, ws + WS_Z);
    out_kernel<<<dim3(16, 16), 256, 0, stream>>>(ws, bias, out);
}